// Round 1
// baseline (107.176 us; speedup 1.0000x reference)
//
#include <hip/hip_runtime.h>
#include <hip/hip_bf16.h>

#define N_NODES 4096
#define BATCH 8
#define FEAT 128
#define CAP 256

// ---------------------------------------------------------------------------
// Kernel 1: dense A [N][N] -> per-row neighbor list (ushort cols) + degree.
// One wave per row; ballot/popc compaction = deterministic, ascending order.
// ---------------------------------------------------------------------------
__global__ __launch_bounds__(256) void build_adj(const float* __restrict__ A,
                                                 unsigned short* __restrict__ nbr,
                                                 int* __restrict__ deg) {
    int lane = threadIdx.x & 63;
    int row = blockIdx.x * 4 + (threadIdx.x >> 6);
    const float* ar = A + (size_t)row * N_NODES;
    unsigned short* lst = nbr + (size_t)row * CAP;
    int cnt = 0;
    for (int c0 = 0; c0 < N_NODES; c0 += 64) {
        int col = c0 + lane;
        bool f = ar[col] > 0.0f;
        unsigned long long mask = __ballot(f);
        int pos = cnt + (int)__popcll(mask & ((1ull << lane) - 1ull));
        if (f && pos < CAP) lst[pos] = (unsigned short)col;
        cnt += (int)__popcll(mask);
    }
    if (lane == 0) deg[row] = cnt < CAP ? cnt : CAP;
}

// ---------------------------------------------------------------------------
// Kernel 2: h = x @ W  (M=B*N rows, K=F=128, C=128), fused epilogue computes
// e_src = h . a_src and e_dst = h . a_dst per row.
// W staged in LDS (64KB). Thread blocking: 4 rows x 8 cols.
// Block: 256 threads = 16 colgroups x 16 rowgroups -> 64 rows/block.
// ---------------------------------------------------------------------------
__global__ __launch_bounds__(256) void gemm_h(const float* __restrict__ x,
                                              const float* __restrict__ W,
                                              const float* __restrict__ a_src,
                                              const float* __restrict__ a_dst,
                                              float* __restrict__ h,
                                              float* __restrict__ es,
                                              float* __restrict__ ed) {
    __shared__ float Wl[FEAT * FEAT];
    int tid = threadIdx.x;
    {
        const float4* Wv = (const float4*)W;
        float4* Wlv = (float4*)Wl;
        for (int i = tid; i < FEAT * FEAT / 4; i += 256) Wlv[i] = Wv[i];
    }
    __syncthreads();

    int colg = tid & 15;
    int rowg = tid >> 4;
    int c0 = colg * 8;
    int m0 = blockIdx.x * 64 + rowg * 4;
    const float* xr = x + (size_t)m0 * FEAT;

    float acc[4][8];
#pragma unroll
    for (int i = 0; i < 4; ++i)
#pragma unroll
        for (int c = 0; c < 8; ++c) acc[i][c] = 0.f;

    for (int k = 0; k < FEAT; k += 4) {
        float4 xv[4];
#pragma unroll
        for (int i = 0; i < 4; ++i) xv[i] = *(const float4*)(xr + i * FEAT + k);
#pragma unroll
        for (int kk = 0; kk < 4; ++kk) {
            float4 wa = *(const float4*)(&Wl[(k + kk) * FEAT + c0]);
            float4 wb = *(const float4*)(&Wl[(k + kk) * FEAT + c0 + 4]);
#pragma unroll
            for (int i = 0; i < 4; ++i) {
                float xs = (&xv[i].x)[kk];
                acc[i][0] += xs * wa.x; acc[i][1] += xs * wa.y;
                acc[i][2] += xs * wa.z; acc[i][3] += xs * wa.w;
                acc[i][4] += xs * wb.x; acc[i][5] += xs * wb.y;
                acc[i][6] += xs * wb.z; acc[i][7] += xs * wb.w;
            }
        }
    }

    float as[8], ad[8];
#pragma unroll
    for (int c = 0; c < 8; ++c) { as[c] = a_src[c0 + c]; ad[c] = a_dst[c0 + c]; }

#pragma unroll
    for (int i = 0; i < 4; ++i) {
        float* hr = h + (size_t)(m0 + i) * FEAT + c0;
        *(float4*)hr = make_float4(acc[i][0], acc[i][1], acc[i][2], acc[i][3]);
        *(float4*)(hr + 4) = make_float4(acc[i][4], acc[i][5], acc[i][6], acc[i][7]);
        float ps = 0.f, pd = 0.f;
#pragma unroll
        for (int c = 0; c < 8; ++c) { ps += acc[i][c] * as[c]; pd += acc[i][c] * ad[c]; }
        // reduce across the 16 colgroup lanes (consecutive lanes within wave)
#pragma unroll
        for (int off = 8; off >= 1; off >>= 1) {
            ps += __shfl_xor(ps, off);
            pd += __shfl_xor(pd, off);
        }
        if (colg == 0) { es[m0 + i] = ps; ed[m0 + i] = pd; }
    }
}

// ---------------------------------------------------------------------------
// Kernel 3: per (b,i) masked-softmax + neighbor aggregation.
// One wave per output row. Lanes 0..d-1 hold one neighbor's logit each
// (chunks of 64 for d>64); shuffle-broadcast alpha_j while each lane owns a
// float2 slice of the 128 output columns.
// blockIdx&7 = batch -> XCD affinity (h[b] = 2MB fits a 4MB per-XCD L2).
// ---------------------------------------------------------------------------
__global__ __launch_bounds__(256) void aggregate(const float* __restrict__ h,
                                                 const float* __restrict__ es,
                                                 const float* __restrict__ ed,
                                                 const unsigned short* __restrict__ nbr,
                                                 const int* __restrict__ deg,
                                                 const float* __restrict__ bias,
                                                 float* __restrict__ out) {
    int lane = threadIdx.x & 63;
    int b = blockIdx.x & 7;
    int i = (blockIdx.x >> 3) * 4 + (threadIdx.x >> 6);

    int d = deg[i];
    const unsigned short* lst = nbr + (size_t)i * CAP;
    float esv = es[b * N_NODES + i];
    const float* edb = ed + b * N_NODES;

    // pass 1: row max of leaky_relu(e_src[i] + e_dst[j], 0.2) over neighbors
    float m = -1e30f;
    for (int c0 = 0; c0 < d; c0 += 64) {
        int j = c0 + lane;
        float z = -1e30f;
        if (j < d) {
            float z0 = esv + edb[lst[j]];
            z = z0 > 0.f ? z0 : 0.2f * z0;
        }
        m = fmaxf(m, z);
    }
#pragma unroll
    for (int off = 32; off >= 1; off >>= 1) m = fmaxf(m, __shfl_xor(m, off));

    // pass 2: p_j = exp(z_j - m); acc += p_j * h[b,j,:]; s = sum p
    const float* hb = h + (size_t)b * N_NODES * FEAT;
    float ax = 0.f, ay = 0.f, s = 0.f;
    for (int c0 = 0; c0 < d; c0 += 64) {
        int j = c0 + lane;
        float p = 0.f;
        int col = 0;
        if (j < d) {
            col = lst[j];
            float z0 = esv + edb[col];
            float z = z0 > 0.f ? z0 : 0.2f * z0;
            p = __expf(z - m);
        }
        s += p;
        int n = d - c0; if (n > 64) n = 64;
        for (int jj = 0; jj < n; ++jj) {
            float pj = __shfl(p, jj);
            int cj = __shfl(col, jj);
            const float2 hv = *(const float2*)(hb + (size_t)cj * FEAT + 2 * lane);
            ax += pj * hv.x;
            ay += pj * hv.y;
        }
    }
#pragma unroll
    for (int off = 32; off >= 1; off >>= 1) s += __shfl_xor(s, off);
    float inv = 1.0f / s;

    float2 bb = *(const float2*)(bias + 2 * lane);
    float ox = ax * inv + bb.x;
    float oy = ay * inv + bb.y;
    ox = ox > 0.f ? ox : 0.3f * ox;
    oy = oy > 0.f ? oy : 0.3f * oy;
    float* orow = out + ((size_t)b * N_NODES + i) * FEAT + 2 * lane;
    *(float2*)orow = make_float2(ox, oy);
}

// ---------------------------------------------------------------------------
extern "C" void kernel_launch(void* const* d_in, const int* in_sizes, int n_in,
                              void* d_out, int out_size, void* d_ws, size_t ws_size,
                              hipStream_t stream) {
    const float* x     = (const float*)d_in[0];
    const float* A     = (const float*)d_in[1];
    const float* W     = (const float*)d_in[2];
    const float* bias  = (const float*)d_in[3];
    const float* a_src = (const float*)d_in[4];
    const float* a_dst = (const float*)d_in[5];
    float* out = (float*)d_out;

    // workspace layout (≈19.2 MB total)
    char* ws = (char*)d_ws;
    float* h  = (float*)ws;                                   // B*N*C floats (16 MB)
    float* es = h + (size_t)BATCH * N_NODES * FEAT;           // B*N floats
    float* ed = es + BATCH * N_NODES;                         // B*N floats
    int*   dg = (int*)(ed + BATCH * N_NODES);                 // N ints
    unsigned short* nb = (unsigned short*)(dg + N_NODES);     // N*CAP ushorts (2 MB)

    hipLaunchKernelGGL(build_adj, dim3(N_NODES / 4), dim3(256), 0, stream, A, nb, dg);
    hipLaunchKernelGGL(gemm_h, dim3(BATCH * N_NODES / 64), dim3(256), 0, stream,
                       x, W, a_src, a_dst, h, es, ed);
    hipLaunchKernelGGL(aggregate, dim3(BATCH * N_NODES / 4), dim3(256), 0, stream,
                       h, es, ed, nb, dg, bias, out);
}

// Round 2
// 73.004 us; speedup vs baseline: 1.4681x; 1.4681x over previous
//
#include <hip/hip_runtime.h>
#include <hip/hip_bf16.h>

#define N_NODES 4096
#define BATCH 8
#define FEAT 128
#define CAP 256

// ---------------------------------------------------------------------------
// Kernel 1: dense A [N][N] -> per-row neighbor list (ushort cols) + degree.
// One wave per row; float4 loads, 4 ballots/iter, popc-prefix compaction.
// ---------------------------------------------------------------------------
__global__ __launch_bounds__(256) void build_adj(const float* __restrict__ A,
                                                 unsigned short* __restrict__ nbr,
                                                 int* __restrict__ deg) {
    int lane = threadIdx.x & 63;
    int row = blockIdx.x * 4 + (threadIdx.x >> 6);
    const float4* ar = (const float4*)(A + (size_t)row * N_NODES);
    unsigned short* lst = nbr + (size_t)row * CAP;
    unsigned long long below = (1ull << lane) - 1ull;
    int cnt = 0;
    for (int c0 = 0; c0 < N_NODES / 4; c0 += 64) {   // 16 iterations
        float4 v = ar[c0 + lane];
        bool f0 = v.x > 0.f, f1 = v.y > 0.f, f2 = v.z > 0.f, f3 = v.w > 0.f;
        unsigned long long m0 = __ballot(f0), m1 = __ballot(f1),
                           m2 = __ballot(f2), m3 = __ballot(f3);
        int pos = cnt + (int)__popcll(m0 & below) + (int)__popcll(m1 & below)
                      + (int)__popcll(m2 & below) + (int)__popcll(m3 & below);
        int colb = 4 * (c0 + lane);
        if (f0) { if (pos < CAP) lst[pos] = (unsigned short)(colb);     ++pos; }
        if (f1) { if (pos < CAP) lst[pos] = (unsigned short)(colb + 1); ++pos; }
        if (f2) { if (pos < CAP) lst[pos] = (unsigned short)(colb + 2); ++pos; }
        if (f3) { if (pos < CAP) lst[pos] = (unsigned short)(colb + 3); ++pos; }
        cnt += (int)__popcll(m0) + (int)__popcll(m1)
             + (int)__popcll(m2) + (int)__popcll(m3);
    }
    if (lane == 0) deg[row] = cnt < CAP ? cnt : CAP;
}

// ---------------------------------------------------------------------------
// Kernel 2: h = x @ W  (M=B*N rows, K=F=128, C=128), fused epilogue computes
// e_src = h . a_src and e_dst = h . a_dst per row.
// W staged in LDS (64KB). Thread blocking: 4 rows x 8 cols.
// ---------------------------------------------------------------------------
__global__ __launch_bounds__(256) void gemm_h(const float* __restrict__ x,
                                              const float* __restrict__ W,
                                              const float* __restrict__ a_src,
                                              const float* __restrict__ a_dst,
                                              float* __restrict__ h,
                                              float* __restrict__ es,
                                              float* __restrict__ ed) {
    __shared__ float Wl[FEAT * FEAT];
    int tid = threadIdx.x;
    {
        const float4* Wv = (const float4*)W;
        float4* Wlv = (float4*)Wl;
        for (int i = tid; i < FEAT * FEAT / 4; i += 256) Wlv[i] = Wv[i];
    }
    __syncthreads();

    int colg = tid & 15;
    int rowg = tid >> 4;
    int c0 = colg * 8;
    int m0 = blockIdx.x * 64 + rowg * 4;
    const float* xr = x + (size_t)m0 * FEAT;

    float acc[4][8];
#pragma unroll
    for (int i = 0; i < 4; ++i)
#pragma unroll
        for (int c = 0; c < 8; ++c) acc[i][c] = 0.f;

    for (int k = 0; k < FEAT; k += 4) {
        float4 xv[4];
#pragma unroll
        for (int i = 0; i < 4; ++i) xv[i] = *(const float4*)(xr + i * FEAT + k);
#pragma unroll
        for (int kk = 0; kk < 4; ++kk) {
            float4 wa = *(const float4*)(&Wl[(k + kk) * FEAT + c0]);
            float4 wb = *(const float4*)(&Wl[(k + kk) * FEAT + c0 + 4]);
#pragma unroll
            for (int i = 0; i < 4; ++i) {
                float xs = (&xv[i].x)[kk];
                acc[i][0] += xs * wa.x; acc[i][1] += xs * wa.y;
                acc[i][2] += xs * wa.z; acc[i][3] += xs * wa.w;
                acc[i][4] += xs * wb.x; acc[i][5] += xs * wb.y;
                acc[i][6] += xs * wb.z; acc[i][7] += xs * wb.w;
            }
        }
    }

    float as[8], ad[8];
#pragma unroll
    for (int c = 0; c < 8; ++c) { as[c] = a_src[c0 + c]; ad[c] = a_dst[c0 + c]; }

#pragma unroll
    for (int i = 0; i < 4; ++i) {
        float* hr = h + (size_t)(m0 + i) * FEAT + c0;
        *(float4*)hr = make_float4(acc[i][0], acc[i][1], acc[i][2], acc[i][3]);
        *(float4*)(hr + 4) = make_float4(acc[i][4], acc[i][5], acc[i][6], acc[i][7]);
        float ps = 0.f, pd = 0.f;
#pragma unroll
        for (int c = 0; c < 8; ++c) { ps += acc[i][c] * as[c]; pd += acc[i][c] * ad[c]; }
#pragma unroll
        for (int off = 8; off >= 1; off >>= 1) {
            ps += __shfl_xor(ps, off);
            pd += __shfl_xor(pd, off);
        }
        if (colg == 0) { es[m0 + i] = ps; ed[m0 + i] = pd; }
    }
}

// ---------------------------------------------------------------------------
// Kernel 3: per (b,i) masked-softmax + neighbor aggregation.
// One wave per output row. 2 neighbors per iter (half-wave each, float4/lane),
// x2 unroll = 4 neighbors per inner iteration, two independent FMA chains.
// z/col cached in registers from the max pass (static-indexed unrolled array).
// blockIdx&7 = batch -> XCD affinity (h[b] = 2MB fits a 4MB per-XCD L2).
// ---------------------------------------------------------------------------
__global__ __launch_bounds__(256) void aggregate(const float* __restrict__ h,
                                                 const float* __restrict__ es,
                                                 const float* __restrict__ ed,
                                                 const unsigned short* __restrict__ nbr,
                                                 const int* __restrict__ deg,
                                                 const float* __restrict__ bias,
                                                 float* __restrict__ out) {
    int lane = threadIdx.x & 63;
    int half = lane >> 5;          // 0: even neighbor slots, 1: odd
    int cl4 = (lane & 31) * 4;     // this lane's 4 output columns
    int b = blockIdx.x & 7;
    int i = (blockIdx.x >> 3) * 4 + (threadIdx.x >> 6);

    int d = deg[i];
    const unsigned short* lst = nbr + (size_t)i * CAP;
    float esv = es[b * N_NODES + i];
    const float* edb = ed + b * N_NODES;

    // pass 1: z_j = leaky_relu(e_src[i]+e_dst[j], 0.2); row max; cache z & col
    float zv0 = -1e30f, zv1 = -1e30f, zv2 = -1e30f, zv3 = -1e30f;
    int cv0 = 0, cv1 = 0, cv2 = 0, cv3 = 0;
    float m = -1e30f;
#define PASS1(c, zz, cc)                                            \
    if (c * 64 < d) {                                               \
        int j = c * 64 + lane;                                      \
        if (j < d) {                                                \
            cc = lst[j];                                            \
            float z0 = esv + edb[cc];                               \
            zz = z0 > 0.f ? z0 : 0.2f * z0;                         \
        }                                                           \
        m = fmaxf(m, zz);                                           \
    }
    PASS1(0, zv0, cv0)
    PASS1(1, zv1, cv1)
    PASS1(2, zv2, cv2)
    PASS1(3, zv3, cv3)
#undef PASS1
#pragma unroll
    for (int off = 32; off >= 1; off >>= 1) m = fmaxf(m, __shfl_xor(m, off));

    // pass 2: p = exp(z-m); acc += p * h[b,col,:]; s = sum p
    const float* hb = h + (size_t)b * N_NODES * FEAT;
    float4 acc0 = make_float4(0.f, 0.f, 0.f, 0.f);
    float4 acc1 = make_float4(0.f, 0.f, 0.f, 0.f);
    float s = 0.f;
#define PASS2(c, zz, cc)                                                       \
    if (c * 64 < d) {                                                          \
        float p = __expf(zz - m);  /* exp(-1e30-m) == 0 for inactive lanes */  \
        s += p;                                                                \
        int n = d - c * 64; if (n > 64) n = 64;                                \
        int nn = (n + 3) & ~3;                                                 \
        for (int jj = 0; jj < nn; jj += 4) {                                   \
            int j0 = jj + half, j1 = jj + 2 + half;                            \
            float p0 = __shfl(p, j0); int cj0 = __shfl(cc, j0);                \
            float p1 = __shfl(p, j1); int cj1 = __shfl(cc, j1);                \
            const float4 h0 = *(const float4*)(hb + (size_t)cj0 * FEAT + cl4); \
            const float4 h1 = *(const float4*)(hb + (size_t)cj1 * FEAT + cl4); \
            acc0.x += p0 * h0.x; acc0.y += p0 * h0.y;                          \
            acc0.z += p0 * h0.z; acc0.w += p0 * h0.w;                          \
            acc1.x += p1 * h1.x; acc1.y += p1 * h1.y;                          \
            acc1.z += p1 * h1.z; acc1.w += p1 * h1.w;                          \
        }                                                                      \
    }
    PASS2(0, zv0, cv0)
    PASS2(1, zv1, cv1)
    PASS2(2, zv2, cv2)
    PASS2(3, zv3, cv3)
#undef PASS2

#pragma unroll
    for (int off = 32; off >= 1; off >>= 1) s += __shfl_xor(s, off);
    float inv = 1.0f / s;

    // merge the two chains, then the two wave halves (lane l <-> l^32 share cols)
    acc0.x += acc1.x; acc0.y += acc1.y; acc0.z += acc1.z; acc0.w += acc1.w;
    acc0.x += __shfl_xor(acc0.x, 32);
    acc0.y += __shfl_xor(acc0.y, 32);
    acc0.z += __shfl_xor(acc0.z, 32);
    acc0.w += __shfl_xor(acc0.w, 32);

    if (lane < 32) {
        float4 bb = *(const float4*)(bias + cl4);
        float o0 = acc0.x * inv + bb.x;
        float o1 = acc0.y * inv + bb.y;
        float o2 = acc0.z * inv + bb.z;
        float o3 = acc0.w * inv + bb.w;
        o0 = o0 > 0.f ? o0 : 0.3f * o0;
        o1 = o1 > 0.f ? o1 : 0.3f * o1;
        o2 = o2 > 0.f ? o2 : 0.3f * o2;
        o3 = o3 > 0.f ? o3 : 0.3f * o3;
        float* orow = out + ((size_t)b * N_NODES + i) * FEAT + cl4;
        *(float4*)orow = make_float4(o0, o1, o2, o3);
    }
}

// ---------------------------------------------------------------------------
extern "C" void kernel_launch(void* const* d_in, const int* in_sizes, int n_in,
                              void* d_out, int out_size, void* d_ws, size_t ws_size,
                              hipStream_t stream) {
    const float* x     = (const float*)d_in[0];
    const float* A     = (const float*)d_in[1];
    const float* W     = (const float*)d_in[2];
    const float* bias  = (const float*)d_in[3];
    const float* a_src = (const float*)d_in[4];
    const float* a_dst = (const float*)d_in[5];
    float* out = (float*)d_out;

    // workspace layout (~18.3 MB total)
    char* ws = (char*)d_ws;
    float* h  = (float*)ws;                                   // B*N*C floats (16 MB)
    float* es = h + (size_t)BATCH * N_NODES * FEAT;           // B*N floats
    float* ed = es + BATCH * N_NODES;                         // B*N floats
    int*   dg = (int*)(ed + BATCH * N_NODES);                 // N ints
    unsigned short* nb = (unsigned short*)(dg + N_NODES);     // N*CAP ushorts (2 MB)

    hipLaunchKernelGGL(build_adj, dim3(N_NODES / 4), dim3(256), 0, stream, A, nb, dg);
    hipLaunchKernelGGL(gemm_h, dim3(BATCH * N_NODES / 64), dim3(256), 0, stream,
                       x, W, a_src, a_dst, h, es, ed);
    hipLaunchKernelGGL(aggregate, dim3(BATCH * N_NODES / 4), dim3(256), 0, stream,
                       h, es, ed, nb, dg, bias, out);
}